// Round 1
// baseline (731.127 us; speedup 1.0000x reference)
//
#include <hip/hip_runtime.h>
#include <hip/hip_bf16.h>
#include <math.h>

typedef unsigned short u16;
typedef __attribute__((ext_vector_type(8))) __bf16 bf16x8;
typedef __attribute__((ext_vector_type(8))) u16 u16x8;
typedef __attribute__((ext_vector_type(4))) u16 u16x4;
typedef __attribute__((ext_vector_type(4))) float fx4;

// B=8, T=1024, D=768, H=12, HD=64, BH=96
__device__ inline u16 f2bf(float f) {
  union { __hip_bfloat16 h; u16 u; } cv;
  cv.h = __float2bfloat16(f);
  return cv.u;
}

// ---------------- prep kernels ----------------

__global__ void cast_x_kernel(const float* __restrict__ x, u16* __restrict__ xb) {
  int i = (blockIdx.x * 256 + threadIdx.x) * 4;
  fx4 v = *(const fx4*)(x + i);
  u16x4 o;
  o[0] = f2bf(v[0]); o[1] = f2bf(v[1]); o[2] = f2bf(v[2]); o[3] = f2bf(v[3]);
  *(u16x4*)(xb + i) = o;
}

// Wt[n*768+k] = W[k*768+n], cast to bf16. Writes coalesced, reads L3-buffered.
__global__ void transpose_w_kernel(const float* __restrict__ W0, const float* __restrict__ W1,
                                   const float* __restrict__ W2, const float* __restrict__ W3,
                                   u16* __restrict__ T0, u16* __restrict__ T1,
                                   u16* __restrict__ T2, u16* __restrict__ T3) {
  int z = blockIdx.y;
  const float* W = (z == 0) ? W0 : (z == 1) ? W1 : (z == 2) ? W2 : W3;
  u16* T = (z == 0) ? T0 : (z == 1) ? T1 : (z == 2) ? T2 : T3;
  int id = blockIdx.x * 256 + threadIdx.x;  // 0..589823
  int n = id / 768, k = id - n * 768;
  T[id] = f2bf(W[k * 768 + n]);
}

// ga1[bh*1024+t] = ga*(gb*grep_a[h]-1)+2, ga=sigmoid(x_h . sum(Wg[:,0:4]) + sum(bg[0:4])), etc.
__global__ void gates_kernel(const float* __restrict__ x, const float* __restrict__ Wg,
                             const float* __restrict__ bg, const float* __restrict__ grep_a,
                             float* __restrict__ ga1) {
  __shared__ float wgA[64], wgB[64], bgs[2];
  int tid = threadIdx.x;
  if (tid < 64) {
    const float* wr = Wg + tid * 8;
    wgA[tid] = wr[0] + wr[1] + wr[2] + wr[3];
    wgB[tid] = wr[4] + wr[5] + wr[6] + wr[7];
  }
  if (tid == 0) {
    bgs[0] = bg[0] + bg[1] + bg[2] + bg[3];
    bgs[1] = bg[4] + bg[5] + bg[6] + bg[7];
  }
  __syncthreads();
  int idx = blockIdx.x * 256 + tid;   // (bh, t), 98304 total
  int bh = idx >> 10, t = idx & 1023;
  int b = bh / 12, h = bh % 12;
  const float* xr = x + (size_t)(b * 1024 + t) * 768 + h * 64;
  float sa = 0.f, sb = 0.f;
  #pragma unroll 8
  for (int d = 0; d < 64; ++d) {
    float xv = xr[d];
    sa += xv * wgA[d];
    sb += xv * wgB[d];
  }
  sa += bgs[0]; sb += bgs[1];
  float gaV = 1.f / (1.f + __expf(-sa));
  float gbV = 1.f / (1.f + __expf(-sb));
  ga1[idx] = gaV * (gbV * grep_a[h] - 1.0f) + 2.0f;
}

// ---------------- bf16 MFMA GEMM: C = A(8192x768) @ W^T-stored(768n x 768k) + bias ----------------
// 128x128 block tile, 4 waves (2x2 of 64x64), 16x16x32 MFMA, BK=32.

__global__ __launch_bounds__(256) void gemm_qkv_kernel(
    const u16* __restrict__ A,
    const u16* __restrict__ Wt0, const u16* __restrict__ Wt1, const u16* __restrict__ Wt2,
    const float* __restrict__ b0, const float* __restrict__ b1, const float* __restrict__ b2,
    u16* __restrict__ outq, u16* __restrict__ outk, u16* __restrict__ outvt) {
  int z = blockIdx.z;
  const u16* Bw = (z == 0) ? Wt0 : (z == 1) ? Wt1 : Wt2;
  const float* bias = (z == 0) ? b0 : (z == 1) ? b1 : b2;
  u16* outp = (z == 0) ? outq : (z == 1) ? outk : outvt;
  __shared__ u16 As[128][40];   // +8 pad: 2-way LDS aliasing only (free)
  __shared__ u16 Bs[128][40];
  int tid = threadIdx.x;
  int w = tid >> 6, lane = tid & 63;
  int ln = lane & 15, quad = lane >> 4;
  int wm = w >> 1, wn = w & 1;
  int m0 = blockIdx.y * 128, n0 = blockIdx.x * 128;
  fx4 acc[4][4];
  #pragma unroll
  for (int i = 0; i < 4; ++i)
    #pragma unroll
    for (int j = 0; j < 4; ++j) acc[i][j] = (fx4){0.f, 0.f, 0.f, 0.f};

  for (int kk = 0; kk < 768; kk += 32) {
    __syncthreads();
    #pragma unroll
    for (int p = 0; p < 2; ++p) {
      int lin = p * 256 + tid;
      int row = lin >> 2, c8 = (lin & 3) * 8;
      *(u16x8*)&As[row][c8] = *(const u16x8*)&A[(size_t)(m0 + row) * 768 + kk + c8];
      *(u16x8*)&Bs[row][c8] = *(const u16x8*)&Bw[(size_t)(n0 + row) * 768 + kk + c8];
    }
    __syncthreads();
    bf16x8 af[4], bfv[4];
    #pragma unroll
    for (int mt = 0; mt < 4; ++mt) af[mt] = *(const bf16x8*)&As[wm * 64 + mt * 16 + ln][quad * 8];
    #pragma unroll
    for (int nt = 0; nt < 4; ++nt) bfv[nt] = *(const bf16x8*)&Bs[wn * 64 + nt * 16 + ln][quad * 8];
    #pragma unroll
    for (int mt = 0; mt < 4; ++mt)
      #pragma unroll
      for (int nt = 0; nt < 4; ++nt)
        acc[mt][nt] = __builtin_amdgcn_mfma_f32_16x16x32_bf16(af[mt], bfv[nt], acc[mt][nt], 0, 0, 0);
  }

  // epilogue: z<2 -> (bh,t,hd) bf16 ; z==2 -> V^T (bh,hd,t) bf16
  #pragma unroll
  for (int mt = 0; mt < 4; ++mt) {
    int mg0 = m0 + wm * 64 + mt * 16 + quad * 4;
    #pragma unroll
    for (int nt = 0; nt < 4; ++nt) {
      int ng = n0 + wn * 64 + nt * 16 + ln;
      float bv = bias[ng];
      int hh = ng >> 6, hd = ng & 63;
      #pragma unroll
      for (int r = 0; r < 4; ++r) {
        int mr = mg0 + r;
        int bb = mr >> 10, t = mr & 1023;
        int bh = bb * 12 + hh;
        float val = acc[mt][nt][r] + bv;
        if (z < 2)
          outp[((size_t)bh * 1024 + t) * 64 + hd] = f2bf(val);
        else
          outp[((size_t)bh * 64 + hd) * 1024 + t] = f2bf(val);
      }
    }
  }
}

__global__ __launch_bounds__(256) void gemm_out_kernel(
    const u16* __restrict__ A, const u16* __restrict__ Bw,
    const float* __restrict__ bias, float* __restrict__ outf) {
  __shared__ u16 As[128][40];
  __shared__ u16 Bs[128][40];
  int tid = threadIdx.x;
  int w = tid >> 6, lane = tid & 63;
  int ln = lane & 15, quad = lane >> 4;
  int wm = w >> 1, wn = w & 1;
  int m0 = blockIdx.y * 128, n0 = blockIdx.x * 128;
  fx4 acc[4][4];
  #pragma unroll
  for (int i = 0; i < 4; ++i)
    #pragma unroll
    for (int j = 0; j < 4; ++j) acc[i][j] = (fx4){0.f, 0.f, 0.f, 0.f};

  for (int kk = 0; kk < 768; kk += 32) {
    __syncthreads();
    #pragma unroll
    for (int p = 0; p < 2; ++p) {
      int lin = p * 256 + tid;
      int row = lin >> 2, c8 = (lin & 3) * 8;
      *(u16x8*)&As[row][c8] = *(const u16x8*)&A[(size_t)(m0 + row) * 768 + kk + c8];
      *(u16x8*)&Bs[row][c8] = *(const u16x8*)&Bw[(size_t)(n0 + row) * 768 + kk + c8];
    }
    __syncthreads();
    bf16x8 af[4], bfv[4];
    #pragma unroll
    for (int mt = 0; mt < 4; ++mt) af[mt] = *(const bf16x8*)&As[wm * 64 + mt * 16 + ln][quad * 8];
    #pragma unroll
    for (int nt = 0; nt < 4; ++nt) bfv[nt] = *(const bf16x8*)&Bs[wn * 64 + nt * 16 + ln][quad * 8];
    #pragma unroll
    for (int mt = 0; mt < 4; ++mt)
      #pragma unroll
      for (int nt = 0; nt < 4; ++nt)
        acc[mt][nt] = __builtin_amdgcn_mfma_f32_16x16x32_bf16(af[mt], bfv[nt], acc[mt][nt], 0, 0, 0);
  }
  #pragma unroll
  for (int mt = 0; mt < 4; ++mt) {
    int mg0 = m0 + wm * 64 + mt * 16 + quad * 4;
    #pragma unroll
    for (int nt = 0; nt < 4; ++nt) {
      int ng = n0 + wn * 64 + nt * 16 + ln;
      float bv = bias[ng];
      #pragma unroll
      for (int r = 0; r < 4; ++r)
        outf[(size_t)(mg0 + r) * 768 + ng] = acc[mt][nt][r] + bv;
    }
  }
}

// ---------------- flash attention with gated transposed rel_bias ----------------
// 1 block = (head bh, 64-q tile). 4 waves, each owns 16 q rows. KT=64 key tiles.

__global__ __launch_bounds__(256) void attn_kernel(
    const u16* __restrict__ qb, const u16* __restrict__ kb, const u16* __restrict__ vtb,
    const float* __restrict__ rel_bias, const float* __restrict__ amask,
    const float* __restrict__ ga1, u16* __restrict__ attn_out) {
  __shared__ u16 Ks[64][72];      // K tile  [key][d], +8 pad
  __shared__ u16 Vs[64][72];      // V^T tile [d][key]
  __shared__ u16 Ps[4][16][72];   // per-wave P round-trip [q][key]
  int g = blockIdx.x;
  // XCD swizzle: all 16 q-tiles of a head land on the same XCD (g%8 fixed per head)
  int xcd = g & 7;
  int idx = g >> 3;
  int bh = xcd * 12 + (idx % 12);
  int qt = idx / 12;
  int b = bh / 12, h = bh % 12;
  int tid = threadIdx.x;
  int w = tid >> 6, lane = tid & 63;
  int ln = lane & 15, quad = lane >> 4;
  int q0 = qt * 64 + w * 16;

  const u16* qrow = qb + ((size_t)bh * 1024 + q0 + ln) * 64 + quad * 8;
  bf16x8 qf0 = *(const bf16x8*)qrow;
  bf16x8 qf1 = *(const bf16x8*)(qrow + 32);
  fx4 ga = *(const fx4*)(ga1 + (size_t)bh * 1024 + q0 + quad * 4);

  fx4 o[4];
  #pragma unroll
  for (int i = 0; i < 4; ++i) o[i] = (fx4){0.f, 0.f, 0.f, 0.f};
  float m_run[4] = {-1e30f, -1e30f, -1e30f, -1e30f};
  float l_run[4] = {0.f, 0.f, 0.f, 0.f};
  const float scaling = 0.125f;  // 64^-0.5

  for (int kt = 0; kt < 16; ++kt) {
    int k0 = kt * 64;
    __syncthreads();
    #pragma unroll
    for (int p = 0; p < 2; ++p) {
      int lin = p * 256 + tid;
      int row = lin >> 3, c8 = (lin & 7) * 8;
      *(u16x8*)&Ks[row][c8] = *(const u16x8*)&kb[((size_t)bh * 1024 + k0 + row) * 64 + c8];
      *(u16x8*)&Vs[row][c8] = *(const u16x8*)&vtb[((size_t)bh * 64 + row) * 1024 + k0 + c8];
    }
    __syncthreads();

    // S = Q K^T  (C-layout: col=key=ln per 16-chunk, row=q=quad*4+r)
    fx4 s[4];
    #pragma unroll
    for (int kf = 0; kf < 4; ++kf) {
      fx4 acc = (fx4){0.f, 0.f, 0.f, 0.f};
      bf16x8 kb0 = *(const bf16x8*)&Ks[kf * 16 + ln][quad * 8];
      bf16x8 kb1 = *(const bf16x8*)&Ks[kf * 16 + ln][32 + quad * 8];
      acc = __builtin_amdgcn_mfma_f32_16x16x32_bf16(qf0, kb0, acc, 0, 0, 0);
      acc = __builtin_amdgcn_mfma_f32_16x16x32_bf16(qf1, kb1, acc, 0, 0, 0);
      s[kf] = acc;
    }

    // scale + gated transposed rel_bias + mask; per-lane float4 over 4 consecutive q
    float mt4[4] = {-1e30f, -1e30f, -1e30f, -1e30f};
    #pragma unroll
    for (int kf = 0; kf < 4; ++kf) {
      int key = k0 + kf * 16 + ln;
      float mk = amask[b * 1024 + key];
      fx4 rb4 = *(const fx4*)(rel_bias + ((size_t)bh * 1024 + key) * 1024 + qt * 64 + w * 16 + quad * 4);
      #pragma unroll
      for (int r = 0; r < 4; ++r) {
        float sv = s[kf][r] * scaling + ga[r] * rb4[r] + mk;
        s[kf][r] = sv;
        mt4[r] = fmaxf(mt4[r], sv);
      }
    }
    #pragma unroll
    for (int mask = 1; mask < 16; mask <<= 1)
      #pragma unroll
      for (int r = 0; r < 4; ++r)
        mt4[r] = fmaxf(mt4[r], __shfl_xor(mt4[r], mask, 64));

    float alpha[4], rs[4];
    #pragma unroll
    for (int r = 0; r < 4; ++r) {
      float mn = fmaxf(m_run[r], mt4[r]);
      alpha[r] = __expf(m_run[r] - mn);
      m_run[r] = mn;
      rs[r] = 0.f;
    }
    #pragma unroll
    for (int kf = 0; kf < 4; ++kf)
      #pragma unroll
      for (int r = 0; r < 4; ++r) {
        float p = __expf(s[kf][r] - m_run[r]);
        s[kf][r] = p;
        rs[r] += p;
      }
    #pragma unroll
    for (int mask = 1; mask < 16; mask <<= 1)
      #pragma unroll
      for (int r = 0; r < 4; ++r)
        rs[r] += __shfl_xor(rs[r], mask, 64);
    #pragma unroll
    for (int r = 0; r < 4; ++r)
      l_run[r] = l_run[r] * alpha[r] + rs[r];

    // P: C-layout -> LDS -> A-layout (per-wave region, no barrier needed)
    #pragma unroll
    for (int kf = 0; kf < 4; ++kf)
      #pragma unroll
      for (int r = 0; r < 4; ++r)
        Ps[w][quad * 4 + r][kf * 16 + ln] = f2bf(s[kf][r]);
    #pragma unroll
    for (int df = 0; df < 4; ++df)
      #pragma unroll
      for (int r = 0; r < 4; ++r)
        o[df][r] *= alpha[r];

    bf16x8 pa0 = *(const bf16x8*)&Ps[w][ln][quad * 8];
    bf16x8 pa1 = *(const bf16x8*)&Ps[w][ln][32 + quad * 8];
    #pragma unroll
    for (int df = 0; df < 4; ++df) {
      bf16x8 vv0 = *(const bf16x8*)&Vs[df * 16 + ln][quad * 8];
      bf16x8 vv1 = *(const bf16x8*)&Vs[df * 16 + ln][32 + quad * 8];
      o[df] = __builtin_amdgcn_mfma_f32_16x16x32_bf16(pa0, vv0, o[df], 0, 0, 0);
      o[df] = __builtin_amdgcn_mfma_f32_16x16x32_bf16(pa1, vv1, o[df], 0, 0, 0);
    }
  }

  float inv[4];
  #pragma unroll
  for (int r = 0; r < 4; ++r) inv[r] = 1.0f / l_run[r];
  #pragma unroll
  for (int df = 0; df < 4; ++df)
    #pragma unroll
    for (int r = 0; r < 4; ++r) {
      int qg = q0 + quad * 4 + r;
      float val = o[df][r] * inv[r];
      attn_out[((size_t)b * 1024 + qg) * 768 + h * 64 + df * 16 + ln] = f2bf(val);
    }
}

// ---------------- launch ----------------

extern "C" void kernel_launch(void* const* d_in, const int* in_sizes, int n_in,
                              void* d_out, int out_size, void* d_ws, size_t ws_size,
                              hipStream_t stream) {
  const float* x         = (const float*)d_in[0];
  const float* attn_mask = (const float*)d_in[1];
  const float* rel_bias  = (const float*)d_in[2];
  const float* Wq        = (const float*)d_in[3];
  const float* bq        = (const float*)d_in[4];
  const float* Wk        = (const float*)d_in[5];
  const float* bk        = (const float*)d_in[6];
  const float* Wv        = (const float*)d_in[7];
  const float* bv        = (const float*)d_in[8];
  const float* Wo        = (const float*)d_in[9];
  const float* bo        = (const float*)d_in[10];
  const float* Wg        = (const float*)d_in[11];
  const float* bg        = (const float*)d_in[12];
  const float* grep_a    = (const float*)d_in[13];

  char* ws = (char*)d_ws;
  const size_t SZ_XD   = (size_t)8192 * 768 * 2;   // 12.6 MB bf16 (B*T, D)
  const size_t SZ_W    = (size_t)768 * 768 * 2;    // 1.18 MB bf16
  u16*   xb   = (u16*)(ws);
  u16*   wqt  = (u16*)(ws + SZ_XD);
  u16*   wkt  = (u16*)(ws + SZ_XD + SZ_W);
  u16*   wvt  = (u16*)(ws + SZ_XD + 2 * SZ_W);
  u16*   wot  = (u16*)(ws + SZ_XD + 3 * SZ_W);
  u16*   qbuf = (u16*)(ws + SZ_XD + 4 * SZ_W);
  u16*   kbuf = (u16*)(ws + 2 * SZ_XD + 4 * SZ_W);
  u16*   vtbuf= (u16*)(ws + 3 * SZ_XD + 4 * SZ_W);
  u16*   attnb= (u16*)(ws + 4 * SZ_XD + 4 * SZ_W);
  float* ga1f = (float*)(ws + 5 * SZ_XD + 4 * SZ_W);  // 96*1024 fp32

  cast_x_kernel<<<6144, 256, 0, stream>>>(x, xb);
  transpose_w_kernel<<<dim3(2304, 4), 256, 0, stream>>>(Wq, Wk, Wv, Wo, wqt, wkt, wvt, wot);
  gates_kernel<<<384, 256, 0, stream>>>(x, Wg, bg, grep_a, ga1f);
  gemm_qkv_kernel<<<dim3(6, 64, 3), 256, 0, stream>>>(xb, wqt, wkt, wvt, bq, bk, bv,
                                                      qbuf, kbuf, vtbuf);
  attn_kernel<<<1536, 256, 0, stream>>>(qbuf, kbuf, vtbuf, rel_bias, attn_mask, ga1f, attnb);
  gemm_out_kernel<<<dim3(6, 64), 256, 0, stream>>>(attnb, wot, bo, (float*)d_out);
}

// Round 2
// 712.960 us; speedup vs baseline: 1.0255x; 1.0255x over previous
//
#include <hip/hip_runtime.h>
#include <hip/hip_bf16.h>
#include <math.h>

typedef unsigned short u16;
typedef __attribute__((ext_vector_type(8))) __bf16 bf16x8;
typedef __attribute__((ext_vector_type(8))) u16 u16x8;
typedef __attribute__((ext_vector_type(4))) u16 u16x4;
typedef __attribute__((ext_vector_type(4))) float fx4;

// B=8, T=1024, D=768, H=12, HD=64, BH=96
__device__ inline u16 f2bf(float f) {
  union { __hip_bfloat16 h; u16 u; } cv;
  cv.h = __float2bfloat16(f);
  return cv.u;
}

// async 16B global -> LDS (wave-uniform LDS base + lane*16)
#define GLDS16(g, l)                                                            \
  __builtin_amdgcn_global_load_lds(                                             \
      (const __attribute__((address_space(1))) void*)(g),                       \
      (__attribute__((address_space(3))) void*)(l), 16, 0, 0)

// ---------------- prep kernels ----------------

__global__ void cast_x_kernel(const float* __restrict__ x, u16* __restrict__ xb) {
  int i = (blockIdx.x * 256 + threadIdx.x) * 4;
  fx4 v = *(const fx4*)(x + i);
  u16x4 o;
  o[0] = f2bf(v[0]); o[1] = f2bf(v[1]); o[2] = f2bf(v[2]); o[3] = f2bf(v[3]);
  *(u16x4*)(xb + i) = o;
}

__global__ void transpose_w_kernel(const float* __restrict__ W0, const float* __restrict__ W1,
                                   const float* __restrict__ W2, const float* __restrict__ W3,
                                   u16* __restrict__ T0, u16* __restrict__ T1,
                                   u16* __restrict__ T2, u16* __restrict__ T3) {
  int z = blockIdx.y;
  const float* W = (z == 0) ? W0 : (z == 1) ? W1 : (z == 2) ? W2 : W3;
  u16* T = (z == 0) ? T0 : (z == 1) ? T1 : (z == 2) ? T2 : T3;
  int id = blockIdx.x * 256 + threadIdx.x;
  int n = id / 768, k = id - n * 768;
  T[id] = f2bf(W[k * 768 + n]);
}

__global__ void gates_kernel(const float* __restrict__ x, const float* __restrict__ Wg,
                             const float* __restrict__ bg, const float* __restrict__ grep_a,
                             float* __restrict__ ga1) {
  __shared__ float wgA[64], wgB[64], bgs[2];
  int tid = threadIdx.x;
  if (tid < 64) {
    const float* wr = Wg + tid * 8;
    wgA[tid] = wr[0] + wr[1] + wr[2] + wr[3];
    wgB[tid] = wr[4] + wr[5] + wr[6] + wr[7];
  }
  if (tid == 0) {
    bgs[0] = bg[0] + bg[1] + bg[2] + bg[3];
    bgs[1] = bg[4] + bg[5] + bg[6] + bg[7];
  }
  __syncthreads();
  int idx = blockIdx.x * 256 + tid;
  int bh = idx >> 10, t = idx & 1023;
  int b = bh / 12, h = bh % 12;
  const float* xr = x + (size_t)(b * 1024 + t) * 768 + h * 64;
  float sa = 0.f, sb = 0.f;
  #pragma unroll 8
  for (int d = 0; d < 64; ++d) {
    float xv = xr[d];
    sa += xv * wgA[d];
    sb += xv * wgB[d];
  }
  sa += bgs[0]; sb += bgs[1];
  float gaV = 1.f / (1.f + __expf(-sa));
  float gbV = 1.f / (1.f + __expf(-sb));
  ga1[idx] = gaV * (gbV * grep_a[h] - 1.0f) + 2.0f;
}

// ---------------- m97-style bf16 MFMA GEMM: 128x128 tile, BK=32, global_load_lds ----------------
// QKV variant: epilogue transposes through LDS for fully-coalesced 16B stores.

__global__ __launch_bounds__(256) void gemm_qkv_kernel(
    const u16* __restrict__ A,
    const u16* __restrict__ Wt0, const u16* __restrict__ Wt1, const u16* __restrict__ Wt2,
    const float* __restrict__ b0, const float* __restrict__ b1, const float* __restrict__ b2,
    u16* __restrict__ outq, u16* __restrict__ outk, u16* __restrict__ outvt) {
  int z = blockIdx.z;
  const u16* Bw = (z == 0) ? Wt0 : (z == 1) ? Wt1 : Wt2;
  const float* bias = (z == 0) ? b0 : (z == 1) ? b1 : b2;
  u16* outp = (z == 0) ? outq : (z == 1) ? outk : outvt;

  __shared__ u16 smem[128 * 132];            // 33792 B; staging aliases the front
  u16* As = smem;                            // [128][32] unpadded (global_load_lds layout)
  u16* Bs = smem + 128 * 32;                 // [128][32]

  int tid = threadIdx.x;
  int w = tid >> 6, lane = tid & 63;
  int ln = lane & 15, quad = lane >> 4;
  int wm = w >> 1, wn = w & 1;
  int m0 = blockIdx.y * 128, n0 = blockIdx.x * 128;
  int srow = w * 16 + (lane >> 2);           // staging row within 64-row half
  int scol = (lane & 3) * 8;                 // staging col (u16 elems)

  fx4 acc[4][4];
  #pragma unroll
  for (int i = 0; i < 4; ++i)
    #pragma unroll
    for (int j = 0; j < 4; ++j) acc[i][j] = (fx4){0.f, 0.f, 0.f, 0.f};

  for (int kk = 0; kk < 768; kk += 32) {
    __syncthreads();
    #pragma unroll
    for (int p = 0; p < 2; ++p) {
      int r = p * 64 + srow;
      GLDS16(A  + (size_t)(m0 + r) * 768 + kk + scol, As + (p * 64 + w * 16) * 32);
      GLDS16(Bw + (size_t)(n0 + r) * 768 + kk + scol, Bs + (p * 64 + w * 16) * 32);
    }
    __syncthreads();
    bf16x8 af[4], bfv[4];
    #pragma unroll
    for (int mt = 0; mt < 4; ++mt) af[mt]  = *(const bf16x8*)&As[(wm * 64 + mt * 16 + ln) * 32 + quad * 8];
    #pragma unroll
    for (int nt = 0; nt < 4; ++nt) bfv[nt] = *(const bf16x8*)&Bs[(wn * 64 + nt * 16 + ln) * 32 + quad * 8];
    #pragma unroll
    for (int mt = 0; mt < 4; ++mt)
      #pragma unroll
      for (int nt = 0; nt < 4; ++nt)
        acc[mt][nt] = __builtin_amdgcn_mfma_f32_16x16x32_bf16(af[mt], bfv[nt], acc[mt][nt], 0, 0, 0);
  }

  // ---- epilogue: C tile -> LDS (stride 132) -> coalesced 16B stores ----
  __syncthreads();
  #pragma unroll
  for (int mt = 0; mt < 4; ++mt) {
    #pragma unroll
    for (int nt = 0; nt < 4; ++nt) {
      int nn = wn * 64 + nt * 16 + ln;
      float bv = bias[n0 + nn];
      #pragma unroll
      for (int r = 0; r < 4; ++r) {
        int mm = wm * 64 + mt * 16 + quad * 4 + r;
        u16 val = f2bf(acc[mt][nt][r] + bv);
        if (z < 2) smem[mm * 132 + nn] = val;   // [m][n]
        else       smem[nn * 132 + mm] = val;   // [n][m]
      }
    }
  }
  __syncthreads();
  int b = m0 >> 10;
  #pragma unroll
  for (int p = 0; p < 4; ++p) {
    int row = p * 32 + (tid >> 3);
    #pragma unroll
    for (int c = 0; c < 2; ++c) {
      int col = c * 64 + (tid & 7) * 8;
      u16x8 v = *(const u16x8*)&smem[row * 132 + col];
      if (z < 2) {
        int ng = n0 + col; int h = ng >> 6, hd = ng & 63;
        int t = (m0 + row) & 1023;
        *(u16x8*)&outp[((size_t)(b * 12 + h) * 1024 + t) * 64 + hd] = v;
      } else {
        int ng = n0 + row; int h = ng >> 6, hd = ng & 63;
        int t = (m0 + col) & 1023;
        *(u16x8*)&outp[((size_t)(b * 12 + h) * 64 + hd) * 1024 + t] = v;
      }
    }
  }
}

// output GEMM: fp32 epilogue is already line-coalesced (16 lanes x 4B = 64B)
__global__ __launch_bounds__(256) void gemm_out_kernel(
    const u16* __restrict__ A, const u16* __restrict__ Bw,
    const float* __restrict__ bias, float* __restrict__ outf) {
  __shared__ u16 As[128 * 32];
  __shared__ u16 Bs[128 * 32];
  int tid = threadIdx.x;
  int w = tid >> 6, lane = tid & 63;
  int ln = lane & 15, quad = lane >> 4;
  int wm = w >> 1, wn = w & 1;
  int m0 = blockIdx.y * 128, n0 = blockIdx.x * 128;
  int srow = w * 16 + (lane >> 2);
  int scol = (lane & 3) * 8;
  fx4 acc[4][4];
  #pragma unroll
  for (int i = 0; i < 4; ++i)
    #pragma unroll
    for (int j = 0; j < 4; ++j) acc[i][j] = (fx4){0.f, 0.f, 0.f, 0.f};

  for (int kk = 0; kk < 768; kk += 32) {
    __syncthreads();
    #pragma unroll
    for (int p = 0; p < 2; ++p) {
      int r = p * 64 + srow;
      GLDS16(A  + (size_t)(m0 + r) * 768 + kk + scol, As + (p * 64 + w * 16) * 32);
      GLDS16(Bw + (size_t)(n0 + r) * 768 + kk + scol, Bs + (p * 64 + w * 16) * 32);
    }
    __syncthreads();
    bf16x8 af[4], bfv[4];
    #pragma unroll
    for (int mt = 0; mt < 4; ++mt) af[mt]  = *(const bf16x8*)&As[(wm * 64 + mt * 16 + ln) * 32 + quad * 8];
    #pragma unroll
    for (int nt = 0; nt < 4; ++nt) bfv[nt] = *(const bf16x8*)&Bs[(wn * 64 + nt * 16 + ln) * 32 + quad * 8];
    #pragma unroll
    for (int mt = 0; mt < 4; ++mt)
      #pragma unroll
      for (int nt = 0; nt < 4; ++nt)
        acc[mt][nt] = __builtin_amdgcn_mfma_f32_16x16x32_bf16(af[mt], bfv[nt], acc[mt][nt], 0, 0, 0);
  }
  #pragma unroll
  for (int mt = 0; mt < 4; ++mt) {
    int mg0 = m0 + wm * 64 + mt * 16 + quad * 4;
    #pragma unroll
    for (int nt = 0; nt < 4; ++nt) {
      int ng = n0 + wn * 64 + nt * 16 + ln;
      float bv = bias[ng];
      #pragma unroll
      for (int r = 0; r < 4; ++r)
        outf[(size_t)(mg0 + r) * 768 + ng] = acc[mt][nt][r] + bv;
    }
  }
}

// ---------------- flash attention with gated transposed rel_bias ----------------

__global__ __launch_bounds__(256) void attn_kernel(
    const u16* __restrict__ qb, const u16* __restrict__ kb, const u16* __restrict__ vtb,
    const float* __restrict__ rel_bias, const float* __restrict__ amask,
    const float* __restrict__ ga1, u16* __restrict__ attn_out) {
  __shared__ u16 Ks[64][72];
  __shared__ u16 Vs[64][72];
  __shared__ u16 Ps[4][16][72];
  int g = blockIdx.x;
  int xcd = g & 7;
  int idx = g >> 3;
  int bh = xcd * 12 + (idx % 12);
  int qt = idx / 12;
  int b = bh / 12, h = bh % 12;
  int tid = threadIdx.x;
  int w = tid >> 6, lane = tid & 63;
  int ln = lane & 15, quad = lane >> 4;
  int q0 = qt * 64 + w * 16;

  const u16* qrow = qb + ((size_t)bh * 1024 + q0 + ln) * 64 + quad * 8;
  bf16x8 qf0 = *(const bf16x8*)qrow;
  bf16x8 qf1 = *(const bf16x8*)(qrow + 32);
  fx4 ga = *(const fx4*)(ga1 + (size_t)bh * 1024 + q0 + quad * 4);
  const float* rb_base = rel_bias + (size_t)bh * 1024 * 1024 + q0 + quad * 4;
  const float* am_base = amask + b * 1024;

  fx4 o[4];
  #pragma unroll
  for (int i = 0; i < 4; ++i) o[i] = (fx4){0.f, 0.f, 0.f, 0.f};
  float m_run[4] = {-1e30f, -1e30f, -1e30f, -1e30f};
  float l_run[4] = {0.f, 0.f, 0.f, 0.f};
  const float scaling = 0.125f;

  for (int kt = 0; kt < 16; ++kt) {
    int k0 = kt * 64;
    // issue rel_bias / mask loads early: independent of MFMA, HBM latency hides under QK
    fx4 rb4[4];
    float mk[4];
    #pragma unroll
    for (int kf = 0; kf < 4; ++kf) {
      int key = k0 + kf * 16 + ln;
      mk[kf] = am_base[key];
      rb4[kf] = *(const fx4*)(rb_base + (size_t)key * 1024);
    }
    __syncthreads();
    #pragma unroll
    for (int p = 0; p < 2; ++p) {
      int lin = p * 256 + tid;
      int row = lin >> 3, c8 = (lin & 7) * 8;
      *(u16x8*)&Ks[row][c8] = *(const u16x8*)&kb[((size_t)bh * 1024 + k0 + row) * 64 + c8];
      *(u16x8*)&Vs[row][c8] = *(const u16x8*)&vtb[((size_t)bh * 64 + row) * 1024 + k0 + c8];
    }
    __syncthreads();

    fx4 s[4];
    #pragma unroll
    for (int kf = 0; kf < 4; ++kf) {
      fx4 a2 = (fx4){0.f, 0.f, 0.f, 0.f};
      bf16x8 kb0 = *(const bf16x8*)&Ks[kf * 16 + ln][quad * 8];
      bf16x8 kb1 = *(const bf16x8*)&Ks[kf * 16 + ln][32 + quad * 8];
      a2 = __builtin_amdgcn_mfma_f32_16x16x32_bf16(qf0, kb0, a2, 0, 0, 0);
      a2 = __builtin_amdgcn_mfma_f32_16x16x32_bf16(qf1, kb1, a2, 0, 0, 0);
      s[kf] = a2;
    }

    float mt4[4] = {-1e30f, -1e30f, -1e30f, -1e30f};
    #pragma unroll
    for (int kf = 0; kf < 4; ++kf) {
      #pragma unroll
      for (int r = 0; r < 4; ++r) {
        float sv = s[kf][r] * scaling + ga[r] * rb4[kf][r] + mk[kf];
        s[kf][r] = sv;
        mt4[r] = fmaxf(mt4[r], sv);
      }
    }
    #pragma unroll
    for (int mask = 1; mask < 16; mask <<= 1)
      #pragma unroll
      for (int r = 0; r < 4; ++r)
        mt4[r] = fmaxf(mt4[r], __shfl_xor(mt4[r], mask, 64));

    float alpha[4], rs[4];
    #pragma unroll
    for (int r = 0; r < 4; ++r) {
      float mn = fmaxf(m_run[r], mt4[r]);
      alpha[r] = __expf(m_run[r] - mn);
      m_run[r] = mn;
      rs[r] = 0.f;
    }
    #pragma unroll
    for (int kf = 0; kf < 4; ++kf)
      #pragma unroll
      for (int r = 0; r < 4; ++r) {
        float p = __expf(s[kf][r] - m_run[r]);
        s[kf][r] = p;
        rs[r] += p;
      }
    #pragma unroll
    for (int mask = 1; mask < 16; mask <<= 1)
      #pragma unroll
      for (int r = 0; r < 4; ++r)
        rs[r] += __shfl_xor(rs[r], mask, 64);
    #pragma unroll
    for (int r = 0; r < 4; ++r)
      l_run[r] = l_run[r] * alpha[r] + rs[r];

    #pragma unroll
    for (int kf = 0; kf < 4; ++kf)
      #pragma unroll
      for (int r = 0; r < 4; ++r)
        Ps[w][quad * 4 + r][kf * 16 + ln] = f2bf(s[kf][r]);
    #pragma unroll
    for (int df = 0; df < 4; ++df)
      #pragma unroll
      for (int r = 0; r < 4; ++r)
        o[df][r] *= alpha[r];

    bf16x8 pa0 = *(const bf16x8*)&Ps[w][ln][quad * 8];
    bf16x8 pa1 = *(const bf16x8*)&Ps[w][ln][32 + quad * 8];
    #pragma unroll
    for (int df = 0; df < 4; ++df) {
      bf16x8 vv0 = *(const bf16x8*)&Vs[df * 16 + ln][quad * 8];
      bf16x8 vv1 = *(const bf16x8*)&Vs[df * 16 + ln][32 + quad * 8];
      o[df] = __builtin_amdgcn_mfma_f32_16x16x32_bf16(pa0, vv0, o[df], 0, 0, 0);
      o[df] = __builtin_amdgcn_mfma_f32_16x16x32_bf16(pa1, vv1, o[df], 0, 0, 0);
    }
  }

  float inv[4];
  #pragma unroll
  for (int r = 0; r < 4; ++r) inv[r] = 1.0f / l_run[r];
  #pragma unroll
  for (int df = 0; df < 4; ++df)
    #pragma unroll
    for (int r = 0; r < 4; ++r) {
      int qg = q0 + quad * 4 + r;
      float val = o[df][r] * inv[r];
      attn_out[((size_t)b * 1024 + qg) * 768 + h * 64 + df * 16 + ln] = f2bf(val);
    }
}

// ---------------- launch ----------------

extern "C" void kernel_launch(void* const* d_in, const int* in_sizes, int n_in,
                              void* d_out, int out_size, void* d_ws, size_t ws_size,
                              hipStream_t stream) {
  const float* x         = (const float*)d_in[0];
  const float* attn_mask = (const float*)d_in[1];
  const float* rel_bias  = (const float*)d_in[2];
  const float* Wq        = (const float*)d_in[3];
  const float* bq        = (const float*)d_in[4];
  const float* Wk        = (const float*)d_in[5];
  const float* bk        = (const float*)d_in[6];
  const float* Wv        = (const float*)d_in[7];
  const float* bv        = (const float*)d_in[8];
  const float* Wo        = (const float*)d_in[9];
  const float* bo        = (const float*)d_in[10];
  const float* Wg        = (const float*)d_in[11];
  const float* bg        = (const float*)d_in[12];
  const float* grep_a    = (const float*)d_in[13];

  char* ws = (char*)d_ws;
  const size_t SZ_XD = (size_t)8192 * 768 * 2;
  const size_t SZ_W  = (size_t)768 * 768 * 2;
  u16*   xb   = (u16*)(ws);
  u16*   wqt  = (u16*)(ws + SZ_XD);
  u16*   wkt  = (u16*)(ws + SZ_XD + SZ_W);
  u16*   wvt  = (u16*)(ws + SZ_XD + 2 * SZ_W);
  u16*   wot  = (u16*)(ws + SZ_XD + 3 * SZ_W);
  u16*   qbuf = (u16*)(ws + SZ_XD + 4 * SZ_W);
  u16*   kbuf = (u16*)(ws + 2 * SZ_XD + 4 * SZ_W);
  u16*   vtbuf= (u16*)(ws + 3 * SZ_XD + 4 * SZ_W);
  u16*   attnb= (u16*)(ws + 4 * SZ_XD + 4 * SZ_W);
  float* ga1f = (float*)(ws + 5 * SZ_XD + 4 * SZ_W);

  cast_x_kernel<<<6144, 256, 0, stream>>>(x, xb);
  transpose_w_kernel<<<dim3(2304, 4), 256, 0, stream>>>(Wq, Wk, Wv, Wo, wqt, wkt, wvt, wot);
  gates_kernel<<<384, 256, 0, stream>>>(x, Wg, bg, grep_a, ga1f);
  gemm_qkv_kernel<<<dim3(6, 64, 3), 256, 0, stream>>>(xb, wqt, wkt, wvt, bq, bk, bv,
                                                      qbuf, kbuf, vtbuf);
  attn_kernel<<<1536, 256, 0, stream>>>(qbuf, kbuf, vtbuf, rel_bias, attn_mask, ga1f, attnb);
  gemm_out_kernel<<<dim3(6, 64), 256, 0, stream>>>(attnb, wot, bo, (float*)d_out);
}